// Round 8
// baseline (270.261 us; speedup 1.0000x reference)
//
#include <hip/hip_runtime.h>
#include <cstdint>

#define B_ 16
#define H_ 224
#define W_ 224
#define C_ 32
#define TS 32      // output tile 32x32, 224 = 7*32
#define RG 47      // data rows/cols in halo region (32 + 7 top + 8 bottom)
#define SR 48      // SAT dim: exclusive 2D prefix needs +1 row & col
#define SP 49      // padded row stride (float4s)

// ---- order-preserving float<->uint encoding (atomic fallback path) ----
__device__ __forceinline__ unsigned int enc_f(float f) {
    unsigned int u = __float_as_uint(f);
    return (u & 0x80000000u) ? ~u : (u | 0x80000000u);
}
__device__ __forceinline__ float dec_f(unsigned int u) {
    u = (u & 0x80000000u) ? (u & 0x7FFFFFFFu) : ~u;
    return __uint_as_float(u);
}

__global__ void init_ws(unsigned int* __restrict__ ws) {
    int t = threadIdx.x;
    if (t < 16) ws[t] = 0xFFFFFFFFu;
    else if (t < 32) ws[t] = 0u;
}

// common block-level min/max reduction over this block's chunk
__device__ __forceinline__ void blk_minmax(const float* __restrict__ x,
                                           float& mn, float& mx) {
    const int b = blockIdx.x;
    const int chunk = blockIdx.y;
    const int chunkElems = (H_ * W_ * C_) / 64;
    const float4* p = (const float4*)(x + (size_t)b * (H_ * W_ * C_) +
                                      (size_t)chunk * chunkElems);
    const int n4 = chunkElems / 4;
    mn = 3.4e38f; mx = -3.4e38f;
    for (int i = threadIdx.x; i < n4; i += 256) {
        float4 v = p[i];
        mn = fminf(mn, fminf(fminf(v.x, v.y), fminf(v.z, v.w)));
        mx = fmaxf(mx, fmaxf(fmaxf(v.x, v.y), fmaxf(v.z, v.w)));
    }
#pragma unroll
    for (int off = 32; off > 0; off >>= 1) {
        mn = fminf(mn, __shfl_down(mn, off));
        mx = fmaxf(mx, __shfl_down(mx, off));
    }
    __shared__ float smn[4], smx[4];
    const int lane = threadIdx.x & 63, wv = threadIdx.x >> 6;
    if (lane == 0) { smn[wv] = mn; smx[wv] = mx; }
    __syncthreads();
    mn = fminf(fminf(smn[0], smn[1]), fminf(smn[2], smn[3]));
    mx = fmaxf(fmaxf(smx[0], smx[1]), fmaxf(smx[2], smx[3]));
}

// slot version: no init kernel, no atomics; block (b,chunk) owns its slot
__global__ __launch_bounds__(256) void minmax_slots(const float* __restrict__ x,
                                                    float* __restrict__ wsf) {
    float mn, mx;
    blk_minmax(x, mn, mx);
    if (threadIdx.x == 0) {
        wsf[blockIdx.y * 16 + blockIdx.x] = mn;
        wsf[1024 + blockIdx.y * 16 + blockIdx.x] = mx;
    }
}

// atomic fallback (ws too small for slots)
__global__ __launch_bounds__(256) void minmax_atomic(const float* __restrict__ x,
                                                     unsigned int* __restrict__ ws) {
    float mn, mx;
    blk_minmax(x, mn, mx);
    if (threadIdx.x == 0) {
        atomicMin(&ws[blockIdx.x], enc_f(mn));
        atomicMax(&ws[16 + blockIdx.x], enc_f(mx));
    }
}

// DPP wave64 inclusive scan (row_shr 1/2/4/8 + row_bcast15/31) — pure VALU
template<int CTRL, int MASK>
__device__ __forceinline__ float dpp_add(float x) {
    int t = __builtin_amdgcn_update_dpp(0, (int)__float_as_uint(x),
                                        CTRL, MASK, 0xf, false);
    return x + __uint_as_float((unsigned)t);
}
template<int CTRL, int MASK>
__device__ __forceinline__ void dpp_step4(float4& v) {
    v.x = dpp_add<CTRL, MASK>(v.x);
    v.y = dpp_add<CTRL, MASK>(v.y);
    v.z = dpp_add<CTRL, MASK>(v.z);
    v.w = dpp_add<CTRL, MASK>(v.w);
}
__device__ __forceinline__ void hscan(float4& v) {
    dpp_step4<0x111, 0xf>(v);   // row_shr:1
    dpp_step4<0x112, 0xf>(v);   // row_shr:2
    dpp_step4<0x114, 0xf>(v);   // row_shr:4
    dpp_step4<0x118, 0xf>(v);   // row_shr:8
    dpp_step4<0x142, 0xa>(v);   // row_bcast15 -> rows 1,3
    dpp_step4<0x143, 0xc>(v);   // row_bcast31 -> rows 2,3
}

__device__ __forceinline__ float4 f4sub(float4 a, float4 b) {
    return make_float4(a.x - b.x, a.y - b.y, a.z - b.z, a.w - b.w);
}
__device__ __forceinline__ float4 f4mul(float4 a, float4 b) {
    return make_float4(a.x * b.x, a.y * b.y, a.z * b.z, a.w * b.w);
}
__device__ __forceinline__ float4 f4cl(float4 a) {   // fmax(a,0)+eps
    return make_float4(fmaxf(a.x, 0.f) + 1e-7f, fmaxf(a.y, 0.f) + 1e-7f,
                       fmaxf(a.z, 0.f) + 1e-7f, fmaxf(a.w, 0.f) + 1e-7f);
}
__device__ __forceinline__ float4 f4cube(float4 a) { // a^3
    return f4mul(f4mul(a, a), a);
}

// Round-8: quad-split — 256-thread blocks, ONE float4 SAT plane (37,632 B)
// -> 4 blocks/CU = 4 independent barrier domains (was 2). P2 is scale-major:
// box = D[r1]-D[r0] with D[r] = S[r][c1]-S[r][c0]; stacked pixels share
// D-rows (scale16: 12 reads vs 16; scale8: 10 vs 16). All intermediates are
// named registers (rule #20). alpha = 0.1*(log2(m16^3*m8)-log2(m2^3*m4)).
template<bool SLOTS>
__global__ __launch_bounds__(256, 4) void lss_kernel(
    const float* __restrict__ x,
    const float* __restrict__ gamma, const float* __restrict__ beta,
    const float* __restrict__ mmean, const float* __restrict__ mvar,
    const unsigned int* __restrict__ ws,
    float* __restrict__ out)
{
    __shared__ float4 SAT[SR][SP];   // 37,632 B -> 4 blocks/CU

    const int bi = blockIdx.x;
    const int grp = bi >> 6, wi = bi & 63;
    const int tile = grp * 8 + (wi & 7);   // bi%8 = tile-in-group -> all 8
    const int cq = (wi >> 3) & 7;          // ch-slices of a tile on same XCD
    const int chbase = cq * 4;
    const int b = tile / 49;
    const int t2 = tile - b * 49;
    const int th0 = (t2 / 7) * TS;
    const int tw0 = (t2 % 7) * TS;
    const int tid = threadIdx.x;
    const int lane = tid & 63, wv = tid >> 6;   // 4 waves

    float mn, mx;
    if (SLOTS) {
        const float* wsf = (const float*)ws;
        float vmn = wsf[lane * 16 + b];
        float vmx = wsf[1024 + lane * 16 + b];
#pragma unroll
        for (int off = 32; off > 0; off >>= 1) {
            vmn = fminf(vmn, __shfl_xor(vmn, off));
            vmx = fmaxf(vmx, __shfl_xor(vmx, off));
        }
        mn = vmn; mx = vmx;
    } else {
        mn = dec_f(ws[b]);
        mx = dec_f(ws[16 + b]);
    }
    const float inv = 1.0f / (mx - mn + 1e-7f);
    const float nmi = -mn * inv;

    const float* xb = x + (size_t)b * (H_ * W_ * C_);
    float* ob = out + (size_t)b * (H_ * W_ * C_);

    // ---- P0: load 16B once, scale, DPP h-scan, write exclusive H-prefix ----
#pragma unroll
    for (int p = 0; p < 12; ++p) {
        const int rr = wv + 4 * p;
        if (rr < RG) {
            const int gh = th0 - 7 + rr;
            const int gw = tw0 - 7 + lane;
            float4 q = make_float4(0.f, 0.f, 0.f, 0.f);
            if (lane < RG && gh >= 0 && gh < H_ && gw >= 0 && gw < W_) {
                q = *(const float4*)(xb + ((size_t)(gh * W_ + gw)) * C_ + chbase);
                q.x = fmaf(q.x, inv, nmi); q.y = fmaf(q.y, inv, nmi);
                q.z = fmaf(q.z, inv, nmi); q.w = fmaf(q.w, inv, nmi);
            }
            hscan(q);
            if (lane < RG) SAT[rr][lane + 1] = q;
            else if (lane == 63) SAT[rr][0] = make_float4(0.f, 0.f, 0.f, 0.f);
        }
    }
    __syncthreads();

    // ---- P1: in-place exclusive vertical scan; 192 scalar columns ----
    if (tid < 192) {
        float* col = (float*)&SAT[0][0] + tid;
        float accv = 0.f;
#pragma unroll
        for (int r = 0; r < SR; ++r) {
            const float t = (r < RG) ? col[r * (SP * 4)] : 0.f;
            col[r * (SP * 4)] = accv;
            accv += t;
        }
    }
    __syncthreads();

    // ---- P2: scale-major consume; 4 pixels/thread (rows h, h+8, h+16, h+24) ----
    {
        const int h = tid >> 5;        // 0..7
        const int wl = tid & 31;

        // BN constants for this quad: out = L*(0.1*t) + (beta - mm*t)
        float4 wq, oq;
        {
            const float4 g4  = *(const float4*)(gamma + chbase);
            const float4 be4 = *(const float4*)(beta  + chbase);
            const float4 mm4 = *(const float4*)(mmean + chbase);
            const float4 mv4 = *(const float4*)(mvar  + chbase);
            float t;
            t = g4.x * rsqrtf(mv4.x + 1e-3f); wq.x = 0.1f * t; oq.x = be4.x - mm4.x * t;
            t = g4.y * rsqrtf(mv4.y + 1e-3f); wq.y = 0.1f * t; oq.y = be4.y - mm4.y * t;
            t = g4.z * rsqrtf(mv4.z + 1e-3f); wq.z = 0.1f * t; oq.z = be4.z - mm4.z * t;
            t = g4.w * rsqrtf(mv4.w + 1e-3f); wq.w = 0.1f * t; oq.w = be4.w - mm4.w * t;
        }

        float4 num0, num1, num2, num3;   // m16^3 * m8 per pixel
        float4 den0, den1, den2, den3;   // m2^3 * m4 per pixel

        // scale 16 (o=0, sc=16): D-rows h+8k, k=0..5; box[pp] = D[k=pp+2]-D[k=pp]
        {
            float4 e0 = f4sub(SAT[h     ][wl + 16], SAT[h     ][wl]);
            float4 e1 = f4sub(SAT[h +  8][wl + 16], SAT[h +  8][wl]);
            float4 e2 = f4sub(SAT[h + 16][wl + 16], SAT[h + 16][wl]);
            float4 e3 = f4sub(SAT[h + 24][wl + 16], SAT[h + 24][wl]);
            float4 e4 = f4sub(SAT[h + 32][wl + 16], SAT[h + 32][wl]);
            float4 e5 = f4sub(SAT[h + 40][wl + 16], SAT[h + 40][wl]);
            num0 = f4cube(f4cl(f4sub(e2, e0)));
            num1 = f4cube(f4cl(f4sub(e3, e1)));
            num2 = f4cube(f4cl(f4sub(e4, e2)));
            num3 = f4cube(f4cl(f4sub(e5, e3)));
        }
        // scale 8 (o=4, sc=8): D-rows h+4+8k, k=0..4; box[pp] = D[k=pp+1]-D[k=pp]
        {
            float4 e0 = f4sub(SAT[h +  4][wl + 12], SAT[h +  4][wl + 4]);
            float4 e1 = f4sub(SAT[h + 12][wl + 12], SAT[h + 12][wl + 4]);
            float4 e2 = f4sub(SAT[h + 20][wl + 12], SAT[h + 20][wl + 4]);
            float4 e3 = f4sub(SAT[h + 28][wl + 12], SAT[h + 28][wl + 4]);
            float4 e4 = f4sub(SAT[h + 36][wl + 12], SAT[h + 36][wl + 4]);
            num0 = f4mul(num0, f4cl(f4sub(e1, e0)));
            num1 = f4mul(num1, f4cl(f4sub(e2, e1)));
            num2 = f4mul(num2, f4cl(f4sub(e3, e2)));
            num3 = f4mul(num3, f4cl(f4sub(e4, e3)));
        }
        // scale 4 (o=6, sc=4): rows h+6+8pp, h+10+8pp; cols wl+6, wl+10
        {
            float4 t0, b0;
            t0 = f4sub(SAT[h +  6][wl + 10], SAT[h +  6][wl + 6]);
            b0 = f4sub(SAT[h + 10][wl + 10], SAT[h + 10][wl + 6]);
            den0 = f4cl(f4sub(b0, t0));
            t0 = f4sub(SAT[h + 14][wl + 10], SAT[h + 14][wl + 6]);
            b0 = f4sub(SAT[h + 18][wl + 10], SAT[h + 18][wl + 6]);
            den1 = f4cl(f4sub(b0, t0));
            t0 = f4sub(SAT[h + 22][wl + 10], SAT[h + 22][wl + 6]);
            b0 = f4sub(SAT[h + 26][wl + 10], SAT[h + 26][wl + 6]);
            den2 = f4cl(f4sub(b0, t0));
            t0 = f4sub(SAT[h + 30][wl + 10], SAT[h + 30][wl + 6]);
            b0 = f4sub(SAT[h + 34][wl + 10], SAT[h + 34][wl + 6]);
            den3 = f4cl(f4sub(b0, t0));
        }
        // scale 2 (o=7, sc=2): rows h+7+8pp, h+9+8pp; cols wl+7, wl+9
        {
            float4 t0, b0;
            t0 = f4sub(SAT[h +  7][wl + 9], SAT[h +  7][wl + 7]);
            b0 = f4sub(SAT[h +  9][wl + 9], SAT[h +  9][wl + 7]);
            den0 = f4mul(den0, f4cube(f4cl(f4sub(b0, t0))));
            t0 = f4sub(SAT[h + 15][wl + 9], SAT[h + 15][wl + 7]);
            b0 = f4sub(SAT[h + 17][wl + 9], SAT[h + 17][wl + 7]);
            den1 = f4mul(den1, f4cube(f4cl(f4sub(b0, t0))));
            t0 = f4sub(SAT[h + 23][wl + 9], SAT[h + 23][wl + 7]);
            b0 = f4sub(SAT[h + 25][wl + 9], SAT[h + 25][wl + 7]);
            den2 = f4mul(den2, f4cube(f4cl(f4sub(b0, t0))));
            t0 = f4sub(SAT[h + 31][wl + 9], SAT[h + 31][wl + 7]);
            b0 = f4sub(SAT[h + 33][wl + 9], SAT[h + 33][wl + 7]);
            den3 = f4mul(den3, f4cube(f4cl(f4sub(b0, t0))));
        }
        // finalize + store (rows h+8pp), one 16B store per pixel
#define FIN(NUM, DEN, ROW) {                                             \
        float4 o4;                                                       \
        o4.x = fmaf(__log2f(NUM.x) - __log2f(DEN.x), wq.x, oq.x);        \
        o4.y = fmaf(__log2f(NUM.y) - __log2f(DEN.y), wq.y, oq.y);        \
        o4.z = fmaf(__log2f(NUM.z) - __log2f(DEN.z), wq.z, oq.z);        \
        o4.w = fmaf(__log2f(NUM.w) - __log2f(DEN.w), wq.w, oq.w);        \
        *(float4*)(ob + ((size_t)((th0 + (ROW)) * W_ + (tw0 + wl))) * C_ \
                   + chbase) = o4; }
        FIN(num0, den0, h);
        FIN(num1, den1, h + 8);
        FIN(num2, den2, h + 16);
        FIN(num3, den3, h + 24);
#undef FIN
    }
}

extern "C" void kernel_launch(void* const* d_in, const int* in_sizes, int n_in,
                              void* d_out, int out_size, void* d_ws, size_t ws_size,
                              hipStream_t stream) {
    const float* x     = (const float*)d_in[0];
    const float* gamma = (const float*)d_in[1];
    const float* beta  = (const float*)d_in[2];
    const float* mmean = (const float*)d_in[3];
    const float* mvar  = (const float*)d_in[4];
    float* out = (float*)d_out;
    unsigned int* ws = (unsigned int*)d_ws;

    if (ws_size >= 8192) {
        hipLaunchKernelGGL(minmax_slots, dim3(16, 64), dim3(256), 0, stream,
                           x, (float*)ws);
        hipLaunchKernelGGL((lss_kernel<true>), dim3(98 * 64), dim3(256), 0, stream,
                           x, gamma, beta, mmean, mvar, ws, out);
    } else {
        hipLaunchKernelGGL(init_ws, dim3(1), dim3(64), 0, stream, ws);
        hipLaunchKernelGGL(minmax_atomic, dim3(16, 64), dim3(256), 0, stream, x, ws);
        hipLaunchKernelGGL((lss_kernel<false>), dim3(98 * 64), dim3(256), 0, stream,
                           x, gamma, beta, mmean, mvar, ws, out);
    }
}

// Round 9
// 261.671 us; speedup vs baseline: 1.0328x; 1.0328x over previous
//
#include <hip/hip_runtime.h>
#include <cstdint>

#define B_ 16
#define H_ 224
#define W_ 224
#define C_ 32
#define TS 32      // output tile 32x32, 224 = 7*32
#define RG 47      // data rows/cols in halo region (32 + 7 top + 8 bottom)
#define SR 48      // SAT dim: exclusive 2D prefix needs +1 row & col
#define SP 49      // padded row stride (float4s)

// ---- order-preserving float<->uint encoding (atomic fallback path) ----
__device__ __forceinline__ unsigned int enc_f(float f) {
    unsigned int u = __float_as_uint(f);
    return (u & 0x80000000u) ? ~u : (u | 0x80000000u);
}
__device__ __forceinline__ float dec_f(unsigned int u) {
    u = (u & 0x80000000u) ? (u & 0x7FFFFFFFu) : ~u;
    return __uint_as_float(u);
}

__global__ void init_ws(unsigned int* __restrict__ ws) {
    int t = threadIdx.x;
    if (t < 16) ws[t] = 0xFFFFFFFFu;
    else if (t < 32) ws[t] = 0u;
}

// common block-level min/max reduction over this block's chunk
__device__ __forceinline__ void blk_minmax(const float* __restrict__ x,
                                           float& mn, float& mx) {
    const int b = blockIdx.x;
    const int chunk = blockIdx.y;
    const int chunkElems = (H_ * W_ * C_) / 64;
    const float4* p = (const float4*)(x + (size_t)b * (H_ * W_ * C_) +
                                      (size_t)chunk * chunkElems);
    const int n4 = chunkElems / 4;
    mn = 3.4e38f; mx = -3.4e38f;
    for (int i = threadIdx.x; i < n4; i += 256) {
        float4 v = p[i];
        mn = fminf(mn, fminf(fminf(v.x, v.y), fminf(v.z, v.w)));
        mx = fmaxf(mx, fmaxf(fmaxf(v.x, v.y), fmaxf(v.z, v.w)));
    }
#pragma unroll
    for (int off = 32; off > 0; off >>= 1) {
        mn = fminf(mn, __shfl_down(mn, off));
        mx = fmaxf(mx, __shfl_down(mx, off));
    }
    __shared__ float smn[4], smx[4];
    const int lane = threadIdx.x & 63, wv = threadIdx.x >> 6;
    if (lane == 0) { smn[wv] = mn; smx[wv] = mx; }
    __syncthreads();
    mn = fminf(fminf(smn[0], smn[1]), fminf(smn[2], smn[3]));
    mx = fmaxf(fmaxf(smx[0], smx[1]), fmaxf(smx[2], smx[3]));
}

// slot version: no init kernel, no atomics; block (b,chunk) owns its slot
__global__ __launch_bounds__(256) void minmax_slots(const float* __restrict__ x,
                                                    float* __restrict__ wsf) {
    float mn, mx;
    blk_minmax(x, mn, mx);
    if (threadIdx.x == 0) {
        wsf[blockIdx.y * 16 + blockIdx.x] = mn;
        wsf[1024 + blockIdx.y * 16 + blockIdx.x] = mx;
    }
}

// atomic fallback (ws too small for slots)
__global__ __launch_bounds__(256) void minmax_atomic(const float* __restrict__ x,
                                                     unsigned int* __restrict__ ws) {
    float mn, mx;
    blk_minmax(x, mn, mx);
    if (threadIdx.x == 0) {
        atomicMin(&ws[blockIdx.x], enc_f(mn));
        atomicMax(&ws[16 + blockIdx.x], enc_f(mx));
    }
}

// DPP wave64 inclusive scan (row_shr 1/2/4/8 + row_bcast15/31) — pure VALU
template<int CTRL, int MASK>
__device__ __forceinline__ float dpp_add(float x) {
    int t = __builtin_amdgcn_update_dpp(0, (int)__float_as_uint(x),
                                        CTRL, MASK, 0xf, false);
    return x + __uint_as_float((unsigned)t);
}
template<int CTRL, int MASK>
__device__ __forceinline__ void dpp_step4(float4& v) {
    v.x = dpp_add<CTRL, MASK>(v.x);
    v.y = dpp_add<CTRL, MASK>(v.y);
    v.z = dpp_add<CTRL, MASK>(v.z);
    v.w = dpp_add<CTRL, MASK>(v.w);
}
__device__ __forceinline__ void hscan(float4& v) {
    dpp_step4<0x111, 0xf>(v);   // row_shr:1
    dpp_step4<0x112, 0xf>(v);   // row_shr:2
    dpp_step4<0x114, 0xf>(v);   // row_shr:4
    dpp_step4<0x118, 0xf>(v);   // row_shr:8
    dpp_step4<0x142, 0xa>(v);   // row_bcast15 -> rows 1,3
    dpp_step4<0x143, 0xc>(v);   // row_bcast31 -> rows 2,3
}

#define CL(a) (fmaxf((a), 0.0f) + 1e-7f)

#define BOXD(S, o, sc, bx) {                                             \
        float4 q00 = S[hl + (o)][wl + (o)];                              \
        float4 q01 = S[hl + (o)][wl + (o) + (sc)];                       \
        float4 q10 = S[hl + (o) + (sc)][wl + (o)];                       \
        float4 q11 = S[hl + (o) + (sc)][wl + (o) + (sc)];                \
        bx.x = q11.x - q01.x - q10.x + q00.x;                            \
        bx.y = q11.y - q01.y - q10.y + q00.y;                            \
        bx.z = q11.z - q01.z - q10.z + q00.z;                            \
        bx.w = q11.w - q01.w - q10.w + q00.w; }

// combined-log: alpha = 0.1*(log2(m16^3*m8) - log2(m2^3*m4)) (exact fold)
#define LSSCOMP(comp, wq, oq, OUT) {                                     \
        const float a2 = CL(b2.comp),  a4 = CL(b4.comp);                 \
        const float a8 = CL(b8.comp),  a16 = CL(b16.comp);               \
        const float Lq = __log2f(a16 * a16 * a16 * a8)                   \
                       - __log2f(a2 * a2 * a2 * a4);                     \
        OUT = fmaf(Lq, wq.comp, oq.comp); }

#define DOQUAD(S, wq, oq, o4) {                                          \
        float4 b2, b4, b8, b16;                                          \
        BOXD(S, 7, 2, b2);                                               \
        BOXD(S, 6, 4, b4);                                               \
        BOXD(S, 4, 8, b8);                                               \
        BOXD(S, 0, 16, b16);                                             \
        LSSCOMP(x, wq, oq, o4.x); LSSCOMP(y, wq, oq, o4.y);              \
        LSSCOMP(z, wq, oq, o4.z); LSSCOMP(w, wq, oq, o4.w); }

// Round-9: 512-thread blocks, ONE float4 SAT plane (37,632 B) -> 4 blocks/CU
// x 8 waves = 32 waves/CU (FULL occupancy; r7/r8 both sat at 16). Per-wave
// code shape identical to r7 (proven 52-VGPR codegen, under the 64-VGPR cap
// that 32 waves requires; launch_bounds(512,8) enforces it). Each block owns
// one 4-channel quad; the 8 sibling blocks of a tile sit 8 apart in blockIdx
// -> same XCD, L2 merges their 16B accesses (r8 evidence: traffic stayed
// ideal at 16B granularity).
template<bool SLOTS>
__global__ __launch_bounds__(512, 8) void lss_kernel(
    const float* __restrict__ x,
    const float* __restrict__ gamma, const float* __restrict__ beta,
    const float* __restrict__ mmean, const float* __restrict__ mvar,
    const unsigned int* __restrict__ ws,
    float* __restrict__ out)
{
    __shared__ float4 SAT[SR][SP];   // 37,632 B -> 4 blocks/CU

    const int bi = blockIdx.x;
    const int grp = bi >> 6, wi = bi & 63;     // group = 8 tiles x 8 quads
    const int tile = grp * 8 + (wi & 7);       // bi%8 = tile-in-group
    const int q = (wi >> 3) & 7;               // channel quad 0..7
    const int chbase = q * 4;
    const int b = tile / 49;
    const int t2 = tile - b * 49;
    const int th0 = (t2 / 7) * TS;
    const int tw0 = (t2 % 7) * TS;
    const int tid = threadIdx.x;
    const int lane = tid & 63, wv = tid >> 6;   // 8 waves

    float mn, mx;
    if (SLOTS) {
        // parallel slot reduce: lane l owns slot l, butterfly across the wave
        const float* wsf = (const float*)ws;
        float vmn = wsf[lane * 16 + b];
        float vmx = wsf[1024 + lane * 16 + b];
#pragma unroll
        for (int off = 32; off > 0; off >>= 1) {
            vmn = fminf(vmn, __shfl_xor(vmn, off));
            vmx = fmaxf(vmx, __shfl_xor(vmx, off));
        }
        mn = vmn; mx = vmx;
    } else {
        mn = dec_f(ws[b]);
        mx = dec_f(ws[16 + b]);
    }
    const float inv = 1.0f / (mx - mn + 1e-7f);
    const float nmi = -mn * inv;

    const float* xb = x + (size_t)b * (H_ * W_ * C_);
    float* ob = out + (size_t)b * (H_ * W_ * C_);

    // ---- P0: load 16B once, scale, DPP h-scan, write exclusive H-prefix ----
#pragma unroll
    for (int p = 0; p < 6; ++p) {
        const int rr = wv + 8 * p;
        if (rr < RG) {
            const int gh = th0 - 7 + rr;
            const int gw = tw0 - 7 + lane;
            float4 q0 = make_float4(0.f, 0.f, 0.f, 0.f);
            if (lane < RG && gh >= 0 && gh < H_ && gw >= 0 && gw < W_) {
                q0 = *(const float4*)(xb + ((size_t)(gh * W_ + gw)) * C_ + chbase);
                q0.x = fmaf(q0.x, inv, nmi); q0.y = fmaf(q0.y, inv, nmi);
                q0.z = fmaf(q0.z, inv, nmi); q0.w = fmaf(q0.w, inv, nmi);
            }
            hscan(q0);
            if (lane < RG) SAT[rr][lane + 1] = q0;
            else if (lane == 63) SAT[rr][0] = make_float4(0.f, 0.f, 0.f, 0.f);
        }
    }
    __syncthreads();

    // ---- P1: in-place exclusive vertical scan; 192 scalar columns
    //          (3 full waves; stride 196 words -> +4 banks/row, 2-way free) ----
    if (tid < 192) {
        float* col = (float*)&SAT[0][0] + tid;
        float accv = 0.f;
#pragma unroll
        for (int r = 0; r < SR; ++r) {
            const float t = (r < RG) ? col[r * (SP * 4)] : 0.f;
            col[r * (SP * 4)] = accv;
            accv += t;
        }
    }
    __syncthreads();

    // ---- P2: 2 pixels/thread; 4 scales from SAT corners,
    //          combined-log + hoisted BN, one 16B store per pixel ----
    {
        const int wl = tid & 31;
        const int hl0 = tid >> 5;             // 0..15

        // BN constants: out = L*(0.1*t) + (beta - mm*t)
        float4 wq, oq;
        {
            const float4 g4  = *(const float4*)(gamma + chbase);
            const float4 be4 = *(const float4*)(beta  + chbase);
            const float4 mm4 = *(const float4*)(mmean + chbase);
            const float4 mv4 = *(const float4*)(mvar  + chbase);
            float t;
            t = g4.x * rsqrtf(mv4.x + 1e-3f); wq.x = 0.1f * t; oq.x = be4.x - mm4.x * t;
            t = g4.y * rsqrtf(mv4.y + 1e-3f); wq.y = 0.1f * t; oq.y = be4.y - mm4.y * t;
            t = g4.z * rsqrtf(mv4.z + 1e-3f); wq.z = 0.1f * t; oq.z = be4.z - mm4.z * t;
            t = g4.w * rsqrtf(mv4.w + 1e-3f); wq.w = 0.1f * t; oq.w = be4.w - mm4.w * t;
        }
#pragma unroll
        for (int pp = 0; pp < 2; ++pp) {
            const int hl = hl0 + pp * 16;
            float4 o4;
            DOQUAD(SAT, wq, oq, o4);
            *(float4*)(ob + ((size_t)((th0 + hl) * W_ + (tw0 + wl))) * C_
                       + chbase) = o4;
        }
    }
}

extern "C" void kernel_launch(void* const* d_in, const int* in_sizes, int n_in,
                              void* d_out, int out_size, void* d_ws, size_t ws_size,
                              hipStream_t stream) {
    const float* x     = (const float*)d_in[0];
    const float* gamma = (const float*)d_in[1];
    const float* beta  = (const float*)d_in[2];
    const float* mmean = (const float*)d_in[3];
    const float* mvar  = (const float*)d_in[4];
    float* out = (float*)d_out;
    unsigned int* ws = (unsigned int*)d_ws;

    if (ws_size >= 8192) {
        hipLaunchKernelGGL(minmax_slots, dim3(16, 64), dim3(256), 0, stream,
                           x, (float*)ws);
        hipLaunchKernelGGL((lss_kernel<true>), dim3(98 * 64), dim3(512), 0, stream,
                           x, gamma, beta, mmean, mvar, ws, out);
    } else {
        hipLaunchKernelGGL(init_ws, dim3(1), dim3(64), 0, stream, ws);
        hipLaunchKernelGGL(minmax_atomic, dim3(16, 64), dim3(256), 0, stream, x, ws);
        hipLaunchKernelGGL((lss_kernel<false>), dim3(98 * 64), dim3(512), 0, stream,
                           x, gamma, beta, mmean, mvar, ws, out);
    }
}

// Round 10
// 260.387 us; speedup vs baseline: 1.0379x; 1.0049x over previous
//
#include <hip/hip_runtime.h>
#include <cstdint>

#define B_ 16
#define H_ 224
#define W_ 224
#define C_ 32
#define TS 32      // output tile 32x32, 224 = 7*32
#define RG 47      // data rows/cols in halo region (32 + 7 top + 8 bottom)
#define SR 48      // SAT dim: exclusive 2D prefix needs +1 row & col
#define SP 49      // padded row stride (float4s)

// ---- order-preserving float<->uint encoding (atomic fallback path) ----
__device__ __forceinline__ unsigned int enc_f(float f) {
    unsigned int u = __float_as_uint(f);
    return (u & 0x80000000u) ? ~u : (u | 0x80000000u);
}
__device__ __forceinline__ float dec_f(unsigned int u) {
    u = (u & 0x80000000u) ? (u & 0x7FFFFFFFu) : ~u;
    return __uint_as_float(u);
}

__global__ void init_ws(unsigned int* __restrict__ ws) {
    int t = threadIdx.x;
    if (t < 16) ws[t] = 0xFFFFFFFFu;
    else if (t < 32) ws[t] = 0u;
}

// common block-level min/max reduction over this block's chunk
__device__ __forceinline__ void blk_minmax(const float* __restrict__ x,
                                           float& mn, float& mx) {
    const int b = blockIdx.x;
    const int chunk = blockIdx.y;
    const int chunkElems = (H_ * W_ * C_) / 64;
    const float4* p = (const float4*)(x + (size_t)b * (H_ * W_ * C_) +
                                      (size_t)chunk * chunkElems);
    const int n4 = chunkElems / 4;
    mn = 3.4e38f; mx = -3.4e38f;
    for (int i = threadIdx.x; i < n4; i += 256) {
        float4 v = p[i];
        mn = fminf(mn, fminf(fminf(v.x, v.y), fminf(v.z, v.w)));
        mx = fmaxf(mx, fmaxf(fmaxf(v.x, v.y), fmaxf(v.z, v.w)));
    }
#pragma unroll
    for (int off = 32; off > 0; off >>= 1) {
        mn = fminf(mn, __shfl_down(mn, off));
        mx = fmaxf(mx, __shfl_down(mx, off));
    }
    __shared__ float smn[4], smx[4];
    const int lane = threadIdx.x & 63, wv = threadIdx.x >> 6;
    if (lane == 0) { smn[wv] = mn; smx[wv] = mx; }
    __syncthreads();
    mn = fminf(fminf(smn[0], smn[1]), fminf(smn[2], smn[3]));
    mx = fmaxf(fmaxf(smx[0], smx[1]), fmaxf(smx[2], smx[3]));
}

// slot version: no init kernel, no atomics; block (b,chunk) owns its slot
__global__ __launch_bounds__(256) void minmax_slots(const float* __restrict__ x,
                                                    float* __restrict__ wsf) {
    float mn, mx;
    blk_minmax(x, mn, mx);
    if (threadIdx.x == 0) {
        wsf[blockIdx.y * 16 + blockIdx.x] = mn;
        wsf[1024 + blockIdx.y * 16 + blockIdx.x] = mx;
    }
}

// atomic fallback (ws too small for slots)
__global__ __launch_bounds__(256) void minmax_atomic(const float* __restrict__ x,
                                                     unsigned int* __restrict__ ws) {
    float mn, mx;
    blk_minmax(x, mn, mx);
    if (threadIdx.x == 0) {
        atomicMin(&ws[blockIdx.x], enc_f(mn));
        atomicMax(&ws[16 + blockIdx.x], enc_f(mx));
    }
}

// ---- packed fp32 (VOP3P) helpers: 2 floats per instruction ----
__device__ __forceinline__ float2 pk_add(float2 a, float2 b) {
    float2 r;
    asm("v_pk_add_f32 %0, %1, %2" : "=v"(r) : "v"(a), "v"(b));
    return r;
}
__device__ __forceinline__ float2 pk_sub(float2 a, float2 b) {
    float2 r;
    asm("v_pk_add_f32 %0, %1, %2 neg_lo:[0,1] neg_hi:[0,1]"
        : "=v"(r) : "v"(a), "v"(b));
    return r;
}
__device__ __forceinline__ float2 pk_mul(float2 a, float2 b) {
    float2 r;
    asm("v_pk_mul_f32 %0, %1, %2" : "=v"(r) : "v"(a), "v"(b));
    return r;
}
__device__ __forceinline__ float2 pk_fma(float2 a, float2 b, float2 c) {
    float2 r;
    asm("v_pk_fma_f32 %0, %1, %2, %3" : "=v"(r) : "v"(a), "v"(b), "v"(c));
    return r;
}
// clamp+eps per half: fmax scalar (no pk_max_f32), eps add packed
__device__ __forceinline__ float2 cl2(float2 a, float2 eps2) {
    float2 m; m.x = fmaxf(a.x, 0.f); m.y = fmaxf(a.y, 0.f);
    return pk_add(m, eps2);
}

// DPP wave64 inclusive scan (row_shr 1/2/4/8 + row_bcast15/31) — pure VALU.
// bound_ctrl=true: invalid-source lanes read 0 (the scan identity) -> the
// canonical GCNDPPCombine-friendly form (single v_add_f32_dpp per step).
template<int CTRL, int MASK>
__device__ __forceinline__ float dpp_add(float x) {
    int t = __builtin_amdgcn_update_dpp(0, (int)__float_as_uint(x),
                                        CTRL, MASK, 0xf, true);
    return x + __uint_as_float((unsigned)t);
}
template<int CTRL, int MASK>
__device__ __forceinline__ void dpp_step4(float4& v) {
    v.x = dpp_add<CTRL, MASK>(v.x);
    v.y = dpp_add<CTRL, MASK>(v.y);
    v.z = dpp_add<CTRL, MASK>(v.z);
    v.w = dpp_add<CTRL, MASK>(v.w);
}
__device__ __forceinline__ void hscan(float4& v) {
    dpp_step4<0x111, 0xf>(v);   // row_shr:1
    dpp_step4<0x112, 0xf>(v);   // row_shr:2
    dpp_step4<0x114, 0xf>(v);   // row_shr:4
    dpp_step4<0x118, 0xf>(v);   // row_shr:8
    dpp_step4<0x142, 0xa>(v);   // row_bcast15 -> rows 1,3
    dpp_step4<0x143, 0xc>(v);   // row_bcast31 -> rows 2,3
}

// packed box from 4 SAT corners: b = (q11-q01) - (q10-q00), lo/hi float2 halves
#define BOXP(S, o, sc, blo, bhi) {                                       \
        float4 q00 = S[hl + (o)][wl + (o)];                              \
        float4 q01 = S[hl + (o)][wl + (o) + (sc)];                       \
        float4 q10 = S[hl + (o) + (sc)][wl + (o)];                       \
        float4 q11 = S[hl + (o) + (sc)][wl + (o) + (sc)];                \
        blo = pk_sub(pk_sub(make_float2(q11.x, q11.y),                   \
                            make_float2(q01.x, q01.y)),                  \
                     pk_sub(make_float2(q10.x, q10.y),                   \
                            make_float2(q00.x, q00.y)));                 \
        bhi = pk_sub(pk_sub(make_float2(q11.z, q11.w),                   \
                            make_float2(q01.z, q01.w)),                  \
                     pk_sub(make_float2(q10.z, q10.w),                   \
                            make_float2(q00.z, q00.w))); }

// combined-log: alpha = 0.1*(log2(m16^3*m8) - log2(m2^3*m4)); packed products
#define DOQUADP(S, wq, oq, eps2, o4) {                                   \
        float2 b2l, b2h, b4l, b4h, b8l, b8h, b16l, b16h;                 \
        BOXP(S, 7, 2, b2l, b2h);                                         \
        BOXP(S, 6, 4, b4l, b4h);                                         \
        BOXP(S, 4, 8, b8l, b8h);                                         \
        BOXP(S, 0, 16, b16l, b16h);                                      \
        const float2 a2l = cl2(b2l, eps2),   a2h = cl2(b2h, eps2);       \
        const float2 a4l = cl2(b4l, eps2),   a4h = cl2(b4h, eps2);       \
        const float2 a8l = cl2(b8l, eps2),   a8h = cl2(b8h, eps2);       \
        const float2 a16l = cl2(b16l, eps2), a16h = cl2(b16h, eps2);     \
        const float2 nl = pk_mul(pk_mul(pk_mul(a16l, a16l), a16l), a8l); \
        const float2 nh = pk_mul(pk_mul(pk_mul(a16h, a16h), a16h), a8h); \
        const float2 dl = pk_mul(pk_mul(pk_mul(a2l, a2l), a2l), a4l);    \
        const float2 dh = pk_mul(pk_mul(pk_mul(a2h, a2h), a2h), a4h);    \
        o4.x = fmaf(__log2f(nl.x) - __log2f(dl.x), wq.x, oq.x);          \
        o4.y = fmaf(__log2f(nl.y) - __log2f(dl.y), wq.y, oq.y);          \
        o4.z = fmaf(__log2f(nh.x) - __log2f(dh.x), wq.z, oq.z);          \
        o4.w = fmaf(__log2f(nh.y) - __log2f(dh.y), wq.w, oq.w); }

// Round-10: r9 structure (512 thr, 1 SAT plane, 4 blocks/CU, 32 waves/CU)
// with VALU-issue cuts: packed-f32 P2/P0 math, float2 P1, combine-friendly DPP.
template<bool SLOTS>
__global__ __launch_bounds__(512, 8) void lss_kernel(
    const float* __restrict__ x,
    const float* __restrict__ gamma, const float* __restrict__ beta,
    const float* __restrict__ mmean, const float* __restrict__ mvar,
    const unsigned int* __restrict__ ws,
    float* __restrict__ out)
{
    __shared__ float4 SAT[SR][SP];   // 37,632 B -> 4 blocks/CU

    const int bi = blockIdx.x;
    const int grp = bi >> 6, wi = bi & 63;     // group = 8 tiles x 8 quads
    const int tile = grp * 8 + (wi & 7);       // bi%8 = tile-in-group
    const int q = (wi >> 3) & 7;               // channel quad 0..7
    const int chbase = q * 4;
    const int b = tile / 49;
    const int t2 = tile - b * 49;
    const int th0 = (t2 / 7) * TS;
    const int tw0 = (t2 % 7) * TS;
    const int tid = threadIdx.x;
    const int lane = tid & 63, wv = tid >> 6;   // 8 waves

    float mn, mx;
    if (SLOTS) {
        // parallel slot reduce: lane l owns slot l, butterfly across the wave
        const float* wsf = (const float*)ws;
        float vmn = wsf[lane * 16 + b];
        float vmx = wsf[1024 + lane * 16 + b];
#pragma unroll
        for (int off = 32; off > 0; off >>= 1) {
            vmn = fminf(vmn, __shfl_xor(vmn, off));
            vmx = fmaxf(vmx, __shfl_xor(vmx, off));
        }
        mn = vmn; mx = vmx;
    } else {
        mn = dec_f(ws[b]);
        mx = dec_f(ws[16 + b]);
    }
    const float inv = 1.0f / (mx - mn + 1e-7f);
    const float nmi = -mn * inv;
    const float2 inv2 = make_float2(inv, inv);
    const float2 nmi2 = make_float2(nmi, nmi);

    const float* xb = x + (size_t)b * (H_ * W_ * C_);
    float* ob = out + (size_t)b * (H_ * W_ * C_);

    // ---- P0: load 16B once, packed scale, DPP h-scan, write excl H-prefix ----
#pragma unroll
    for (int p = 0; p < 6; ++p) {
        const int rr = wv + 8 * p;
        if (rr < RG) {
            const int gh = th0 - 7 + rr;
            const int gw = tw0 - 7 + lane;
            float4 q0 = make_float4(0.f, 0.f, 0.f, 0.f);
            if (lane < RG && gh >= 0 && gh < H_ && gw >= 0 && gw < W_) {
                q0 = *(const float4*)(xb + ((size_t)(gh * W_ + gw)) * C_ + chbase);
                const float2 lo = pk_fma(make_float2(q0.x, q0.y), inv2, nmi2);
                const float2 hi = pk_fma(make_float2(q0.z, q0.w), inv2, nmi2);
                q0 = make_float4(lo.x, lo.y, hi.x, hi.y);
            }
            hscan(q0);
            if (lane < RG) SAT[rr][lane + 1] = q0;
            else if (lane == 63) SAT[rr][0] = make_float4(0.f, 0.f, 0.f, 0.f);
        }
    }
    __syncthreads();

    // ---- P1: in-place exclusive vertical scan; 2 adjacent scalar columns
    //          per thread via float2 (96 threads; b64 LDS ops, packed adds) ----
    if (tid < 96) {
        float2* colp = (float2*)((float*)&SAT[0][0] + tid * 2);
        float2 accv = make_float2(0.f, 0.f);
#pragma unroll
        for (int r = 0; r < SR; ++r) {
            const float2 t = (r < RG) ? colp[r * (SP * 2)]
                                      : make_float2(0.f, 0.f);
            colp[r * (SP * 2)] = accv;
            accv = pk_add(accv, t);
        }
    }
    __syncthreads();

    // ---- P2: 2 pixels/thread; packed 4-scale consume + fused BN,
    //          one 16B store per pixel ----
    {
        const int wl = tid & 31;
        const int hl0 = tid >> 5;             // 0..15
        const float2 eps2 = make_float2(1e-7f, 1e-7f);

        // BN constants: out = L*(0.1*t) + (beta - mm*t)
        float4 wq, oq;
        {
            const float4 g4  = *(const float4*)(gamma + chbase);
            const float4 be4 = *(const float4*)(beta  + chbase);
            const float4 mm4 = *(const float4*)(mmean + chbase);
            const float4 mv4 = *(const float4*)(mvar  + chbase);
            float t;
            t = g4.x * rsqrtf(mv4.x + 1e-3f); wq.x = 0.1f * t; oq.x = be4.x - mm4.x * t;
            t = g4.y * rsqrtf(mv4.y + 1e-3f); wq.y = 0.1f * t; oq.y = be4.y - mm4.y * t;
            t = g4.z * rsqrtf(mv4.z + 1e-3f); wq.z = 0.1f * t; oq.z = be4.z - mm4.z * t;
            t = g4.w * rsqrtf(mv4.w + 1e-3f); wq.w = 0.1f * t; oq.w = be4.w - mm4.w * t;
        }
#pragma unroll
        for (int pp = 0; pp < 2; ++pp) {
            const int hl = hl0 + pp * 16;
            float4 o4;
            DOQUADP(SAT, wq, oq, eps2, o4);
            *(float4*)(ob + ((size_t)((th0 + hl) * W_ + (tw0 + wl))) * C_
                       + chbase) = o4;
        }
    }
}

extern "C" void kernel_launch(void* const* d_in, const int* in_sizes, int n_in,
                              void* d_out, int out_size, void* d_ws, size_t ws_size,
                              hipStream_t stream) {
    const float* x     = (const float*)d_in[0];
    const float* gamma = (const float*)d_in[1];
    const float* beta  = (const float*)d_in[2];
    const float* mmean = (const float*)d_in[3];
    const float* mvar  = (const float*)d_in[4];
    float* out = (float*)d_out;
    unsigned int* ws = (unsigned int*)d_ws;

    if (ws_size >= 8192) {
        hipLaunchKernelGGL(minmax_slots, dim3(16, 64), dim3(256), 0, stream,
                           x, (float*)ws);
        hipLaunchKernelGGL((lss_kernel<true>), dim3(98 * 64), dim3(512), 0, stream,
                           x, gamma, beta, mmean, mvar, ws, out);
    } else {
        hipLaunchKernelGGL(init_ws, dim3(1), dim3(64), 0, stream, ws);
        hipLaunchKernelGGL(minmax_atomic, dim3(16, 64), dim3(256), 0, stream, x, ws);
        hipLaunchKernelGGL((lss_kernel<false>), dim3(98 * 64), dim3(512), 0, stream,
                           x, gamma, beta, mmean, mvar, ws, out);
    }
}